// Round 2
// baseline (620.410 us; speedup 1.0000x reference)
//
#include <hip/hip_runtime.h>
#include <math.h>

#define H_ 2048
#define W_ 2448
#define HW (H_*W_)          // 5013504
#define HW4 (HW/4)          // 1253376 = 1224 * 1024 exactly

typedef float f4 __attribute__((ext_vector_type(4)));

// f32-exact einsum coefficients (sin/cos evaluated at f32-rounded 2*pi*k/4):
#define SIN2_C  (-8.7422777e-08f)   // sin(pi_f32)
#define COS1_C  (-4.3711388e-08f)   // cos(pi/2_f32)
#define COS3_C  ( 1.1924881e-08f)   // cos(3pi/2_f32)
#define TWO_PI_F   6.2831854820251465f
#define PI_HALF_F  1.5707963705062866f
#define PI3HALF_F  4.7123889923095703f
#define SCALE_F    2.5464790894703254f
#define BG_THR_F   0.05f

// Streaming restructure: planes visited ONE AT A TIME with 4 KB/wave bursts
// (16 KB/block contiguous per plane) instead of 24 simultaneous 1 KB streams.
// Plane stride = 153*2^17 B keeps channel/bank bits identical across planes,
// so the old pattern hit one bank with 24 interleaved rows (row thrash).
// All reductions are streamed: s/c linear sums, thr pairwise tree via 2
// partials, graycode bits packed into an int + prefix-XOR at the end.

__global__ __launch_bounds__(256)
void cg_kernel(const float* __restrict__ img, f4* __restrict__ out4) {
    const f4* in4 = (const f4*)img;
    // 16 pixels per thread: 4 f4-groups at stride 256 f4 (1 KB/wave/instr bursts)
    const size_t base = (size_t)blockIdx.x * 1024 + threadIdx.x;

    f4 A[4], B[4];

#define LOADP(dst, p) \
    _Pragma("unroll") \
    for (int k = 0; k < 4; ++k) \
        dst[k] = __builtin_nontemporal_load(&in4[(size_t)(p) * HW4 + base + (size_t)(k) * 256]);

#define FORALL \
    _Pragma("unroll") for (int k = 0; k < 4; ++k) \
    _Pragma("unroll") for (int j = 0; j < 4; ++j)

    float sc[4][4], cc[4][4], sr[4][4], cr[4][4];
    float pair[4][4], s0123[4][4], thr[4][4];

    // phase-shift planes: identical op/assoc order to the verified kernel:
    //   sc = (i1 + SIN2*i2) - i3
    //   cc = ((i0 + COS1*i1) - i2) + COS3*i3
    //   thr = 0.125*(((i0+i1)+(i2+i3)) + ((i4+i5)+(i6+i7)))   (pairwise)
#define P0(t) FORALL { float v = t[k][j]; cc[k][j] = v; pair[k][j] = v; }
#define P1(t) FORALL { float v = t[k][j]; sc[k][j] = v; \
    cc[k][j] = __fadd_rn(cc[k][j], __fmul_rn(COS1_C, v)); \
    s0123[k][j] = __fadd_rn(pair[k][j], v); }
#define P2(t) FORALL { float v = t[k][j]; \
    sc[k][j] = __fadd_rn(sc[k][j], __fmul_rn(SIN2_C, v)); \
    cc[k][j] = __fsub_rn(cc[k][j], v); pair[k][j] = v; }
#define P3(t) FORALL { float v = t[k][j]; \
    sc[k][j] = __fsub_rn(sc[k][j], v); \
    cc[k][j] = __fadd_rn(cc[k][j], __fmul_rn(COS3_C, v)); \
    s0123[k][j] = __fadd_rn(s0123[k][j], __fadd_rn(pair[k][j], v)); }
#define P4(t) FORALL { float v = t[k][j]; cr[k][j] = v; pair[k][j] = v; }
#define P5(t) FORALL { float v = t[k][j]; sr[k][j] = v; \
    cr[k][j] = __fadd_rn(cr[k][j], __fmul_rn(COS1_C, v)); \
    thr[k][j] = __fadd_rn(pair[k][j], v); }   /* thr temporarily holds s45 */
#define P6(t) FORALL { float v = t[k][j]; \
    sr[k][j] = __fadd_rn(sr[k][j], __fmul_rn(SIN2_C, v)); \
    cr[k][j] = __fsub_rn(cr[k][j], v); pair[k][j] = v; }
#define P7(t) FORALL { float v = t[k][j]; \
    sr[k][j] = __fsub_rn(sr[k][j], v); \
    cr[k][j] = __fadd_rn(cr[k][j], __fmul_rn(COS3_C, v)); \
    float s4567 = __fadd_rn(thr[k][j], __fadd_rn(pair[k][j], v)); \
    thr[k][j] = __fmul_rn(0.125f, __fadd_rn(s0123[k][j], s4567)); }

    // graycode: collect raw (g > thr) bits; prefix-XOR deferred to the end
#define GCB(t, bit) FORALL { R[k][j] |= (t[k][j] > thr[k][j]) ? (1 << (bit)) : 0; }

    LOADP(A, 0);
    LOADP(B, 1);  P0(A);
    LOADP(A, 2);  P1(B);
    LOADP(B, 3);  P2(A);
    LOADP(A, 4);  P3(B);
    LOADP(B, 5);  P4(A);
    LOADP(A, 6);  P5(B);
    LOADP(B, 7);  P6(A);
    LOADP(A, 8);  P7(B);
    LOADP(B, 9);            // depth-2 prefetch covers the atan2 block below

    float psc[4][4], psr[4][4], msk[4][4];
    int R[4][4];
    FORALL {
        float scv = sc[k][j], ccv = cc[k][j], srv = sr[k][j], crv = cr[k][j];
        float bgc = __fmul_rn(0.5f, __fsqrt_rn(__fadd_rn(__fmul_rn(scv, scv), __fmul_rn(ccv, ccv))));
        float bgr = __fmul_rn(0.5f, __fsqrt_rn(__fadd_rn(__fmul_rn(srv, srv), __fmul_rn(crv, crv))));
        msk[k][j] = (bgc > BG_THR_F || bgr > BG_THR_F) ? 1.0f : 0.0f;
        float a = -atan2f(scv, ccv);
        if (a < 0.0f) a = __fadd_rn(a, TWO_PI_F);
        psc[k][j] = a;
        float b = -atan2f(srv, crv);
        if (b < 0.0f) b = __fadd_rn(b, TWO_PI_F);
        psr[k][j] = b;
        R[k][j] = 0;
    }

    // col graycode planes 8..15 -> bits 7..0 ; row planes 16..23 -> bits 15..8
    GCB(A, 7);                 // p=8
    LOADP(A, 10); GCB(B, 6);   // p=9
    LOADP(B, 11); GCB(A, 5);   // p=10
    LOADP(A, 12); GCB(B, 4);   // p=11
    LOADP(B, 13); GCB(A, 3);   // p=12
    LOADP(A, 14); GCB(B, 2);   // p=13
    LOADP(B, 15); GCB(A, 1);   // p=14
    LOADP(A, 16); GCB(B, 0);   // p=15
    LOADP(B, 17); GCB(A, 15);  // p=16
    LOADP(A, 18); GCB(B, 14);  // p=17
    LOADP(B, 19); GCB(A, 13);  // p=18
    LOADP(A, 20); GCB(B, 12);  // p=19
    LOADP(B, 21); GCB(A, 11);  // p=20
    LOADP(A, 22); GCB(B, 10);  // p=21
    LOADP(B, 23); GCB(A, 9);   // p=22
    GCB(B, 8);                 // p=23

#pragma unroll
    for (int k = 0; k < 4; ++k) {
        float co[4], ro[4];
#pragma unroll
        for (int j = 0; j < 4; ++j) {
            int Rv = R[k][j];
            // prefix-XOR from MSB: bit(7-i) = r0^...^ri  (== cumulative gray decode)
            int vc = Rv & 0xFF;
            vc ^= vc >> 1; vc ^= vc >> 2; vc ^= vc >> 4;
            int vr = (Rv >> 8) & 0xFF;
            vr ^= vr >> 1; vr ^= vr >> 2; vr ^= vr >> 4;
            int k1c = vc >> 1, k2c = (vc + 1) >> 1;   // k1 = v2>>1 exactly
            int k1r = vr >> 1, k2r = (vr + 1) >> 1;

            float a = psc[k][j];
            float ac;
            if (a <= PI_HALF_F)      ac = __fmul_rn(TWO_PI_F, (float)k2c);
            else if (a < PI3HALF_F)  ac = __fmul_rn(TWO_PI_F, (float)k1c);
            else                     ac = __fsub_rn(__fmul_rn(TWO_PI_F, (float)k2c), TWO_PI_F);
            float b = psr[k][j];
            float ar;
            if (b <= PI_HALF_F)      ar = __fmul_rn(TWO_PI_F, (float)k2r);
            else if (b < PI3HALF_F)  ar = __fmul_rn(TWO_PI_F, (float)k1r);
            else                     ar = __fsub_rn(__fmul_rn(TWO_PI_F, (float)k2r), TWO_PI_F);

            a = __fadd_rn(a, ac);
            b = __fadd_rn(b, ar);
            float m = msk[k][j];
            co[j] = __fmul_rn(__fmul_rn(a, m), SCALE_F);
            ro[j] = __fmul_rn(__fmul_rn(b, m), SCALE_F);
        }
        // output layout (H, W, 2): f4-pixel q -> out floats [8q .. 8q+7]
        size_t q = base + (size_t)k * 256;
        f4 o0 = {co[0], ro[0], co[1], ro[1]};
        f4 o1 = {co[2], ro[2], co[3], ro[3]};
        __builtin_nontemporal_store(o0, &out4[2 * q]);
        __builtin_nontemporal_store(o1, &out4[2 * q + 1]);
    }
}

extern "C" void kernel_launch(void* const* d_in, const int* in_sizes, int n_in,
                              void* d_out, int out_size, void* d_ws, size_t ws_size,
                              hipStream_t stream) {
    const float* img = (const float*)d_in[0];
    f4* out = (f4*)d_out;
    dim3 grid(HW4 / 1024), block(256);   // 1224 blocks
    hipLaunchKernelGGL(cg_kernel, grid, block, 0, stream, img, out);
}

// Round 3
// 593.524 us; speedup vs baseline: 1.0453x; 1.0453x over previous
//
#include <hip/hip_runtime.h>
#include <math.h>

#define H_ 2048
#define W_ 2448
#define HW (H_*W_)          // 5013504
#define HW2 (HW/2)          // 2506752 = 9792 * 256 exactly

typedef float f2 __attribute__((ext_vector_type(2)));
typedef float f4 __attribute__((ext_vector_type(4)));

// f32-exact einsum coefficients (sin/cos evaluated at f32-rounded 2*pi*k/4):
//   delta_f32 = {0, 1.5707964f, 3.1415927f, 4.7123890f}
//   sin = {0, 1, -8.742278e-8, -1},  cos = {1, -4.3711388e-8, -1, +1.1924881e-8}
#define SIN2_C  (-8.7422777e-08f)   // sin(pi_f32)
#define COS1_C  (-4.3711388e-08f)   // cos(pi/2_f32)
#define COS3_C  ( 1.1924881e-08f)   // cos(3pi/2_f32)
#define TWO_PI_F   6.2831854820251465f
#define PI_HALF_F  1.5707963705062866f   // f32(pi/2)
#define PI3HALF_F  4.7123889923095703f   // f32(3*pi/2)
#define SCALE_F    2.5464790894703254f   // f32(16/(2*pi))
#define BG_THR_F   0.05f

// Round-0 structure (best measured: all 24 loads up front, nt load/store,
// identical f32 op order) but 2 pixels/thread via dwordx2 loads:
//   - per-thread data VGPRs halve (96 -> 48); launch_bounds(256,4) locks
//     >=4 waves/SIMD (vs est. 2 for the f4 version)
//   - 2.4x more waves chip-wide -> more MLP under contention-inflated latency
//   - output becomes exactly one f4 per thread (floats 4t..4t+3)

__global__ __launch_bounds__(256, 4)
void cg_kernel(const float* __restrict__ img, f4* __restrict__ out4) {
    const int t = blockIdx.x * 256 + threadIdx.x;   // grid covers HW2 exactly
    const f2* in2 = (const f2*)img;

    f2 p[8];
#pragma unroll
    for (int i = 0; i < 8; ++i)
        p[i] = __builtin_nontemporal_load(&in2[(size_t)i * HW2 + t]);
    f2 g[16];
#pragma unroll
    for (int i = 0; i < 16; ++i)
        g[i] = __builtin_nontemporal_load(&in2[(size_t)(8 + i) * HW2 + t]);

    float col[2], row[2];
#pragma unroll
    for (int j = 0; j < 2; ++j) {
        const float i0 = p[0][j], i1 = p[1][j], i2 = p[2][j], i3 = p[3][j];
        const float i4 = p[4][j], i5 = p[5][j], i6 = p[6][j], i7 = p[7][j];

        // s = i1 + SIN2*i2 - i3 ; c = ((i0 + COS1*i1) - i2) + COS3*i3
        // non-fused f32 ops: comparisons downstream are tie-sensitive
        float sc = __fsub_rn(__fadd_rn(i1, __fmul_rn(SIN2_C, i2)), i3);
        float cc = __fadd_rn(__fsub_rn(__fadd_rn(i0, __fmul_rn(COS1_C, i1)), i2),
                             __fmul_rn(COS3_C, i3));
        float sr = __fsub_rn(__fadd_rn(i5, __fmul_rn(SIN2_C, i6)), i7);
        float cr = __fadd_rn(__fsub_rn(__fadd_rn(i4, __fmul_rn(COS1_C, i5)), i6),
                             __fmul_rn(COS3_C, i7));

        float bgc = __fmul_rn(0.5f, __fsqrt_rn(__fadd_rn(__fmul_rn(sc, sc), __fmul_rn(cc, cc))));
        float bgr = __fmul_rn(0.5f, __fsqrt_rn(__fadd_rn(__fmul_rn(sr, sr), __fmul_rn(cr, cr))));
        float msk = (bgc > BG_THR_F || bgr > BG_THR_F) ? 1.0f : 0.0f;

        // pairwise (np-style) mean of the 8 phase-shift planes
        float thr = __fmul_rn(0.125f,
            __fadd_rn(__fadd_rn(__fadd_rn(i0, i1), __fadd_rn(i2, i3)),
                      __fadd_rn(__fadd_rn(i4, i5), __fadd_rn(i6, i7))));

        float psc = -atan2f(sc, cc);
        if (psc < 0.0f) psc = __fadd_rn(psc, TWO_PI_F);
        float psr = -atan2f(sr, cr);
        if (psr < 0.0f) psr = __fadd_rn(psr, TWO_PI_F);

        // graycode cumulative-XOR decode, ratio = {128,...,1}
        int cumc = 0, v2c = 0, k1c = 0;
        int cumr = 0, v2r = 0, k1r = 0;
#pragma unroll
        for (int i = 0; i < 8; ++i) {
            cumc ^= (g[i][j]     > thr) ? 1 : 0;
            cumr ^= (g[8 + i][j] > thr) ? 1 : 0;
            v2c += cumc << (7 - i);
            v2r += cumr << (7 - i);
            if (i < 7) { k1c += cumc << (6 - i); k1r += cumr << (6 - i); }
        }
        int k2c = (v2c + 1) >> 1;
        int k2r = (v2r + 1) >> 1;

        float ac;
        if (psc <= PI_HALF_F)      ac = __fmul_rn(TWO_PI_F, (float)k2c);
        else if (psc < PI3HALF_F)  ac = __fmul_rn(TWO_PI_F, (float)k1c);
        else                       ac = __fsub_rn(__fmul_rn(TWO_PI_F, (float)k2c), TWO_PI_F);
        float ar;
        if (psr <= PI_HALF_F)      ar = __fmul_rn(TWO_PI_F, (float)k2r);
        else if (psr < PI3HALF_F)  ar = __fmul_rn(TWO_PI_F, (float)k1r);
        else                       ar = __fsub_rn(__fmul_rn(TWO_PI_F, (float)k2r), TWO_PI_F);

        psc = __fadd_rn(psc, ac);
        psr = __fadd_rn(psr, ar);

        col[j] = __fmul_rn(__fmul_rn(psc, msk), SCALE_F);
        row[j] = __fmul_rn(__fmul_rn(psr, msk), SCALE_F);
    }

    // pixels 2t, 2t+1 -> out floats [4t .. 4t+3] == out4[t]
    f4 o = {col[0], row[0], col[1], row[1]};
    __builtin_nontemporal_store(o, &out4[t]);
}

extern "C" void kernel_launch(void* const* d_in, const int* in_sizes, int n_in,
                              void* d_out, int out_size, void* d_ws, size_t ws_size,
                              hipStream_t stream) {
    const float* img = (const float*)d_in[0];
    f4* out = (f4*)d_out;
    dim3 grid(HW2 / 256), block(256);   // 9792 blocks
    hipLaunchKernelGGL(cg_kernel, grid, block, 0, stream, img, out);
}